// Round 3
// baseline (134.602 us; speedup 1.0000x reference)
//
#include <hip/hip_runtime.h>
#include <hip/hip_bf16.h>
#include <math.h>

// Problem constants (from reference):
//   B=128, S=1024, D1=64 (SIZE1), N=2048, D0=512 (SIZE0)
#define B_   128
#define S_   1024
#define D1_  64
#define N_   2048
#define D0_  512

// -----------------------------------------------------------------------------
// Kernel 0: v[b,s] = sum_d enc[b, current_index, d] * W[d, s]
// Bias dropped: adds a per-row constant to logits -> cancels in softmax.
// -----------------------------------------------------------------------------
__global__ __launch_bounds__(D0_) void prep_kernel(
    const float* __restrict__ enc, const int* __restrict__ cur_idx,
    const float* __restrict__ W, float* __restrict__ v)
{
    __shared__ float temp[D1_];
    const int b = blockIdx.x;
    const int t = threadIdx.x;           // 0..511
    const int ci = *cur_idx;
    if (t < D1_) {
        temp[t] = enc[(size_t)b * (S_ * D1_) + (size_t)ci * D1_ + t];
    }
    __syncthreads();
    float acc = 0.f;
#pragma unroll
    for (int d = 0; d < D1_; ++d) {
        acc += temp[d] * W[d * D0_ + t];
    }
    v[b * D0_ + t] = acc;
}

// -----------------------------------------------------------------------------
// Kernel 1: logits[b,n] = dot(neighbor[b,n,:], v[b,:])
// Lane-owns-row GEMV: each lane accumulates ONE row's full dot product.
// No cross-lane reduction at all -> loads never wait on a shuffle chain.
// v[b] lives in LDS (2 KB), read with a uniform index (broadcast, no
// conflicts, lgkm pipe). 1024 blocks x 256 threads; block -> 256 consecutive
// rows; 8 blocks per batch (2048/256), so b is uniform per block.
// -----------------------------------------------------------------------------
__global__ __launch_bounds__(256) void logits_kernel(
    const float* __restrict__ nb, const float* __restrict__ v,
    float* __restrict__ out)
{
    __shared__ float4 vs[D0_ / 4];               // 2 KB
    const int t = threadIdx.x;
    const int b = blockIdx.x >> 3;               // 8 blocks per batch

    if (t < D0_ / 4) {
        vs[t] = ((const float4*)(v + (size_t)b * D0_))[t];
    }
    __syncthreads();

    const size_t row = (size_t)blockIdx.x * 256 + t;   // lane-contiguous rows
    const float4* __restrict__ r = (const float4*)(nb + row * D0_);

    float acc = 0.f;
#pragma unroll 16
    for (int k = 0; k < D0_ / 4; ++k) {
        const float4 a = r[k];
        const float4 w = vs[k];
        acc += a.x * w.x + a.y * w.y + a.z * w.z + a.w * w.w;
    }
    out[row] = acc;                               // coalesced store
}

// -----------------------------------------------------------------------------
// Kernel 2: in-place row softmax over N_=2048 elements. 128 blocks (one per
// batch) x 256 threads; each thread owns 8 elements.
// -----------------------------------------------------------------------------
__global__ __launch_bounds__(256) void softmax_kernel(float* __restrict__ out)
{
    float* row = out + (size_t)blockIdx.x * N_;
    const int t = threadIdx.x;
    const int wave = t >> 6, lane = t & 63;

    float vals[8];
    float m = -INFINITY;
#pragma unroll
    for (int i = 0; i < 8; ++i) {
        vals[i] = row[t + i * 256];
        m = fmaxf(m, vals[i]);
    }
#pragma unroll
    for (int off = 32; off; off >>= 1) m = fmaxf(m, __shfl_xor(m, off));

    __shared__ float redm[4];
    __shared__ float reds[4];
    if (lane == 0) redm[wave] = m;
    __syncthreads();
    m = fmaxf(fmaxf(redm[0], redm[1]), fmaxf(redm[2], redm[3]));

    float s = 0.f;
#pragma unroll
    for (int i = 0; i < 8; ++i) {
        vals[i] = __expf(vals[i] - m);
        s += vals[i];
    }
#pragma unroll
    for (int off = 32; off; off >>= 1) s += __shfl_xor(s, off);
    if (lane == 0) reds[wave] = s;
    __syncthreads();
    s = reds[0] + reds[1] + reds[2] + reds[3];

    const float inv = 1.0f / s;
#pragma unroll
    for (int i = 0; i < 8; ++i) row[t + i * 256] = vals[i] * inv;
}

extern "C" void kernel_launch(void* const* d_in, const int* in_sizes, int n_in,
                              void* d_out, int out_size, void* d_ws, size_t ws_size,
                              hipStream_t stream)
{
    // Input order per setup_inputs():
    //   0: encoder_outputs          (B,S,D1) f32
    //   1: current_index            scalar int
    //   2: encoder_outputs_neighbor (B,N,D0) f32
    //   3: neighbor_num             scalar int (== N_, unused)
    //   4: W                        (D1,D0) f32
    //   5: b                        (D1,) f32  -- cancels in softmax, unused
    const float* enc     = (const float*)d_in[0];
    const int*   cur_idx = (const int*)d_in[1];
    const float* nb      = (const float*)d_in[2];
    const float* W       = (const float*)d_in[4];
    float*       out     = (float*)d_out;
    float*       v       = (float*)d_ws;   // B_*D0_*4 = 256 KB scratch

    prep_kernel<<<B_, D0_, 0, stream>>>(enc, cur_idx, W, v);
    logits_kernel<<<(B_ * N_) / 256, 256, 0, stream>>>(nb, v, out);
    softmax_kernel<<<B_, 256, 0, stream>>>(out);
}

// Round 4
// 101.093 us; speedup vs baseline: 1.3315x; 1.3315x over previous
//
#include <hip/hip_runtime.h>
#include <hip/hip_bf16.h>
#include <math.h>

// Problem constants (from reference):
//   B=128, S=1024, D1=64 (SIZE1), N=2048, D0=512 (SIZE0)
#define B_   128
#define S_   1024
#define D1_  64
#define N_   2048
#define D0_  512

// -----------------------------------------------------------------------------
// Kernel 0: v[b,s] = sum_d enc[b, current_index, d] * W[d, s]
// Bias dropped: adds a per-row constant to logits -> cancels in softmax.
// -----------------------------------------------------------------------------
__global__ __launch_bounds__(D0_) void prep_kernel(
    const float* __restrict__ enc, const int* __restrict__ cur_idx,
    const float* __restrict__ W, float* __restrict__ v)
{
    __shared__ float temp[D1_];
    const int b = blockIdx.x;
    const int t = threadIdx.x;           // 0..511
    const int ci = *cur_idx;
    if (t < D1_) {
        temp[t] = enc[(size_t)b * (S_ * D1_) + (size_t)ci * D1_ + t];
    }
    __syncthreads();
    float acc = 0.f;
#pragma unroll
    for (int d = 0; d < D1_; ++d) {
        acc += temp[d] * W[d * D0_ + t];
    }
    v[b * D0_ + t] = acc;
}

// -----------------------------------------------------------------------------
// Kernel 1: logits[b,n] = dot(neighbor[b,n,:], v[b,:])
// One-shot blocks (R0 structure kept): block = 256 thr = 4 waves = 16 rows.
// v[b] staged in LDS once per block (batch is block-uniform: 128 blocks/batch).
// Each row owned by a 16-lane group: lane loads 8 float4 of its row
// (coalesced: 4 rows x 256B segments per instruction = same 128B-line count
// as a contiguous 1KB wave access), dots against LDS v (16 distinct 16B
// lines -> 2-way bank aliasing = free), then a 4-step 16-lane butterfly.
// Per row: 2 vmem loads (was 4), 1 shuffle-chain step count 4 (was 6).
// -----------------------------------------------------------------------------
__global__ __launch_bounds__(256) void logits_kernel(
    const float* __restrict__ nb, const float* __restrict__ v,
    float* __restrict__ out)
{
    __shared__ float4 vs[D0_ / 4];               // 2 KB
    const int t = threadIdx.x;
    const int b = blockIdx.x >> 7;               // 128 blocks per batch

    if (t < D0_ / 4) {
        vs[t] = ((const float4*)(v + (size_t)b * D0_))[t];
    }
    __syncthreads();

    const int lane = t & 63;
    const int wave = t >> 6;
    const int sub  = lane & 15;                  // chunk index within row
    const int rsel = lane >> 4;                  // which of the wave's 4 rows
    const size_t row = (size_t)blockIdx.x * 16 + wave * 4 + rsel;
    const float4* __restrict__ r = (const float4*)(nb + row * D0_);

    float acc = 0.f;
#pragma unroll
    for (int k = 0; k < 8; ++k) {
        const float4 a = r[sub + 16 * k];
        const float4 w = vs[sub + 16 * k];
        acc += a.x * w.x + a.y * w.y + a.z * w.z + a.w * w.w;
    }

#pragma unroll
    for (int off = 8; off; off >>= 1) acc += __shfl_xor(acc, off);

    if (sub == 0) out[row] = acc;
}

// -----------------------------------------------------------------------------
// Kernel 2: in-place row softmax over N_=2048 elements. 128 blocks (one per
// batch) x 256 threads; each thread owns 8 elements.
// -----------------------------------------------------------------------------
__global__ __launch_bounds__(256) void softmax_kernel(float* __restrict__ out)
{
    float* row = out + (size_t)blockIdx.x * N_;
    const int t = threadIdx.x;
    const int wave = t >> 6, lane = t & 63;

    float vals[8];
    float m = -INFINITY;
#pragma unroll
    for (int i = 0; i < 8; ++i) {
        vals[i] = row[t + i * 256];
        m = fmaxf(m, vals[i]);
    }
#pragma unroll
    for (int off = 32; off; off >>= 1) m = fmaxf(m, __shfl_xor(m, off));

    __shared__ float redm[4];
    __shared__ float reds[4];
    if (lane == 0) redm[wave] = m;
    __syncthreads();
    m = fmaxf(fmaxf(redm[0], redm[1]), fmaxf(redm[2], redm[3]));

    float s = 0.f;
#pragma unroll
    for (int i = 0; i < 8; ++i) {
        vals[i] = __expf(vals[i] - m);
        s += vals[i];
    }
#pragma unroll
    for (int off = 32; off; off >>= 1) s += __shfl_xor(s, off);
    if (lane == 0) reds[wave] = s;
    __syncthreads();
    s = reds[0] + reds[1] + reds[2] + reds[3];

    const float inv = 1.0f / s;
#pragma unroll
    for (int i = 0; i < 8; ++i) row[t + i * 256] = vals[i] * inv;
}

extern "C" void kernel_launch(void* const* d_in, const int* in_sizes, int n_in,
                              void* d_out, int out_size, void* d_ws, size_t ws_size,
                              hipStream_t stream)
{
    // Input order per setup_inputs():
    //   0: encoder_outputs          (B,S,D1) f32
    //   1: current_index            scalar int
    //   2: encoder_outputs_neighbor (B,N,D0) f32
    //   3: neighbor_num             scalar int (== N_, unused)
    //   4: W                        (D1,D0) f32
    //   5: b                        (D1,) f32  -- cancels in softmax, unused
    const float* enc     = (const float*)d_in[0];
    const int*   cur_idx = (const int*)d_in[1];
    const float* nb      = (const float*)d_in[2];
    const float* W       = (const float*)d_in[4];
    float*       out     = (float*)d_out;
    float*       v       = (float*)d_ws;   // B_*D0_*4 = 256 KB scratch

    prep_kernel<<<B_, D0_, 0, stream>>>(enc, cur_idx, W, v);
    logits_kernel<<<(B_ * N_) / 16, 256, 0, stream>>>(nb, v, out);
    softmax_kernel<<<B_, 256, 0, stream>>>(out);
}